// Round 11
// baseline (312.154 us; speedup 1.0000x reference)
//
#include <hip/hip_runtime.h>

// ActionVectorQuantizer: z [8*32768, 256] f32, emb [8, 256] f32
// out0 = emb[argmin_c ||z-e_c||^2] (f32), out1 = idx stored as f32.
//
// Math (verified 5x, f64-exact products, first-occurrence tie-break):
// lane = (c2=bit0, g=bits1..5); lane owns dims 8g..8g+7 and codes
// {4*c2+m}. Per token: in-lane f64 dots, fold masks {2,4} + mask {32}
// plain sum. Per 4-token batch: transpose-fold masks {8,16} (token
// tau = 2*b3+b4, dup over b5), packed-key argmin masks {1,2,4}.
//
// Round-11: occupancy 2.5 -> 5 waves/SIMD. Round 10's LDS (32KB/block)
// capped residency at 10 waves/CU (Occ 20%, 2200 cyc/token of wall vs
// ~200 of issue). BATCH 8->4 halves LDS (16KB/block -> 10 blocks/CU);
// e-table in f32 + remat cvt (round-7-proven, fits 64 VGPR) so the
// (128,5) cap (102 VGPR) can't spill. vmcnt ledger per {4L,5S} batch:
// S S | w4 CT S | w9 CT S |... | w9 CT | w5 CT.

#define NC    8
#define DIM   256
#define TPW   32           // tokens per wave
#define WPB   2            // waves per block
#define THREADS (WPB * 64)
#define BATCH 4

typedef float f32x4 __attribute__((ext_vector_type(4)));

#define WAITV(n) do { \
    asm volatile("s_waitcnt vmcnt(" #n ")" ::: "memory"); \
    __builtin_amdgcn_sched_barrier(0); \
} while (0)

__global__ __launch_bounds__(THREADS, 5)
void vq_kernel(const float* __restrict__ z, const float* __restrict__ emb,
               float* __restrict__ zq, float* __restrict__ fidx)
{
    // 2 waves x 2 buffers x 4 tokens x 1KB = 16 KB/block -> 10 blocks/CU
    __shared__ float lds[WPB][2][BATCH * DIM];

    const int lane = threadIdx.x & 63;
    const int w    = threadIdx.x >> 6;
    const int wid  = blockIdx.x * WPB + w;

    const int c2 = lane & 1;
    const int b1 = (lane >> 1) & 1, b2 = (lane >> 2) & 1;
    const int b3 = (lane >> 3) & 1, b4 = (lane >> 4) & 1, b5 = (lane >> 5) & 1;
    const int kappa = 4 * c2 + 2 * b1 + b2;   // code this lane owns post-fold
    const int gidx  = lane & 7;               // lane within 8-lane group
    const int tau   = 2 * b3 + b4;            // batch-local token post-transpose

    // emb fragments in f32 (remat cvt at use keeps VGPR under the 102 cap)
    float e32[4][8];
#pragma unroll
    for (int m = 0; m < 4; ++m) {
        const int row = 4 * c2 + m;
        const float4 ea = *reinterpret_cast<const float4*>(emb + row * DIM + 4 * lane);
        const float4 eb = *reinterpret_cast<const float4*>(emb + row * DIM + 4 * (lane ^ 1));
        e32[m][0] = ea.x; e32[m][1] = ea.y; e32[m][2] = ea.z; e32[m][3] = ea.w;
        e32[m][4] = eb.x; e32[m][5] = eb.y; e32[m][6] = eb.z; e32[m][7] = eb.w;
    }

    // ||e_kappa||^2 (one-time, f64-exact; plain 64-lane sum)
    double es[4];
#pragma unroll
    for (int m = 0; m < 4; ++m) {
        double s = 0.0;
#pragma unroll
        for (int j = 0; j < 8; ++j) {
            const double e = (double)e32[m][j];
            s += e * e;
        }
        es[m] = s;
    }
    double est[2];
#pragma unroll
    for (int i = 0; i < 2; ++i) {
        double keep = b1 ? es[i + 2] : es[i];
        double send = b1 ? es[i]     : es[i + 2];
        est[i] = keep + __shfl_xor(send, 2, 64);
    }
    double esv = (b2 ? est[1] : est[0]) + __shfl_xor(b2 ? est[0] : est[1], 4, 64);
    esv += __shfl_xor(esv, 8, 64);
    esv += __shfl_xor(esv, 16, 64);
    esv += __shfl_xor(esv, 32, 64);
    const double esq_my = esv;   // ||e_kappa||^2, exact f64

    const long long tok0 = (long long)wid * TPW;

    double val[BATCH];

    // ---- stage one 4-token batch into a per-wave LDS buffer ----
    // global_load_lds width=16: LDS dst is wave-uniform base + lane*16
    // -> linear row layout (exactly how we read it back).
    auto STAGE = [&](int bufi, int bidx) {
        const float* s = z + (tok0 + (long long)bidx * BATCH) * DIM + 4 * lane;
        float* d = &lds[w][bufi][0];
#pragma unroll
        for (int t = 0; t < BATCH; ++t)
            __builtin_amdgcn_global_load_lds(
                (const unsigned int*)(s + (size_t)t * DIM),
                (unsigned int*)(d + t * DIM), 16, 0, 0);
    };

    // ---- compute 4 tokens from an LDS buffer -> val[0..3] ----
    auto COMPUTE = [&](int bufi) {
        const float* bb = &lds[w][bufi][0];
#pragma unroll
        for (int t = 0; t < BATCH; ++t) {
            const float4 cA = *reinterpret_cast<const float4*>(bb + t * DIM + 4 * lane);
            const float4 cB = *reinterpret_cast<const float4*>(bb + t * DIM + 4 * (lane ^ 1));
            double acc[4];
            {
                const double z0 = cA.x, z1 = cA.y, z2 = cA.z, z3 = cA.w;
#pragma unroll
                for (int m = 0; m < 4; ++m)
                    acc[m] = (z0 * (double)e32[m][0] + z1 * (double)e32[m][1])
                           + (z2 * (double)e32[m][2] + z3 * (double)e32[m][3]);
            }
            {
                const double z4 = cB.x, z5 = cB.y, z6 = cB.z, z7 = cB.w;
#pragma unroll
                for (int m = 0; m < 4; ++m)
                    acc[m] += (z4 * (double)e32[m][4] + z5 * (double)e32[m][5])
                            + (z6 * (double)e32[m][6] + z7 * (double)e32[m][7]);
            }
            // fold masks {2,4} -> per-lane partial (code kappa, 32 dims)
            double ft[2];
#pragma unroll
            for (int i = 0; i < 2; ++i) {
                double keep = b1 ? acc[i + 2] : acc[i];
                double send = b1 ? acc[i]     : acc[i + 2];
                ft[i] = keep + __shfl_xor(send, 2, 64);
            }
            double v = (b2 ? ft[1] : ft[0]) + __shfl_xor(b2 ? ft[0] : ft[1], 4, 64);
            // mask {32} plain sum -> (code kappa, 64 dims), dup over b5
            val[t] = v + __shfl_xor(v, 32, 64);
        }
    };

    // ---- batched tail: 2-level transpose-fold, argmin, stores ----
    auto TAIL = [&](int bidx) {
        double tt[2];
#pragma unroll
        for (int i = 0; i < 2; ++i) {
            double keep = b3 ? val[i + 2] : val[i];
            double send = b3 ? val[i]     : val[i + 2];
            tt[i] = keep + __shfl_xor(send, 8, 64);
        }
        const double dot = (b4 ? tt[1] : tt[0]) + __shfl_xor(b4 ? tt[0] : tt[1], 16, 64);

        // argmin of ||z||^2 + ||e||^2 - 2 z.e == argmin of ||e||^2 - 2 z.e
        const double dist = esq_my - 2.0 * dot;

        // order-preserving f64 -> u64 key, code idx in low 3 bits
        unsigned long long u = (unsigned long long)__double_as_longlong(dist);
        u = (u >> 63) ? ~u : (u | 0x8000000000000000ULL);
        unsigned long long key = (u & ~7ULL) | (unsigned long long)kappa;
#pragma unroll
        for (int m = 1; m <= 4; m <<= 1) {
            unsigned long long ok = __shfl_xor(key, m, 64);
            key = (ok < key) ? ok : key;
        }
        const int widx = (int)(key & 7ULL);   // winner for token tau

        // cooperative z_q write: 16 lanes (b5 dup) own token tau; lane
        // writes chunks gidx+8*b5+16*j -> each instr = 4 rows x 256B.
        // Nontemporal full-line stores: never re-read, keep L3 for z.
        const long long row = tok0 + (long long)bidx * BATCH + tau;
        float* qrow = zq + row * DIM;
        const float* erow = emb + widx * DIM;
#pragma unroll
        for (int j = 0; j < 4; ++j) {
            const int ch = gidx + 8 * b5 + 16 * j;
            const f32x4 q = *reinterpret_cast<const f32x4*>(erow + 4 * ch);
            __builtin_nontemporal_store(q, reinterpret_cast<f32x4*>(qrow + 4 * ch));
        }
        if (gidx == 0 && b5 == 0) fidx[row] = (float)widx;   // 4 lanes, 4 rows
    };

    // ---- pipelined schedule: counted vmcnt, never 0 mid-loop ----
    // per batch: 4 loads (STAGE), 5 stores (TAIL)
    STAGE(0, 0); STAGE(1, 1);

    WAITV(4); COMPUTE(0); TAIL(0); STAGE(0, 2);   // younger: b1's 4L
    WAITV(9); COMPUTE(1); TAIL(1); STAGE(1, 3);   // younger: 5S + 4L
    WAITV(9); COMPUTE(0); TAIL(2); STAGE(0, 4);
    WAITV(9); COMPUTE(1); TAIL(3); STAGE(1, 5);
    WAITV(9); COMPUTE(0); TAIL(4); STAGE(0, 6);
    WAITV(9); COMPUTE(1); TAIL(5); STAGE(1, 7);
    WAITV(9); COMPUTE(0); TAIL(6);                // younger: 5S + 4L
    WAITV(5); COMPUTE(1); TAIL(7);                // younger: tail6's 5S
}

extern "C" void kernel_launch(void* const* d_in, const int* in_sizes, int n_in,
                              void* d_out, int out_size, void* d_ws, size_t ws_size,
                              hipStream_t stream)
{
    const float* z   = (const float*)d_in[0];
    const float* emb = (const float*)d_in[1];
    float* out = (float*)d_out;

    const long long ntok = (long long)in_sizes[0] / DIM;   // 262144
    float* zq   = out;
    float* fidx = out + (size_t)ntok * DIM;

    const int blocks = (int)(ntok / (TPW * WPB));          // 4096

    vq_kernel<<<blocks, THREADS, 0, stream>>>(z, emb, zq, fidx);
}

// Round 12
// 98.505 us; speedup vs baseline: 3.1689x; 3.1689x over previous
//
#include <hip/hip_runtime.h>

// ActionVectorQuantizer: z [8*32768, 256] f32, emb [8, 256] f32
// out0 = emb[argmin_c ||z-e_c||^2] (f32), out1 = idx stored as f32.
//
// Math (verified 6x, f64-exact products, first-occurrence tie-break):
// lane = (c2=bit0, g=bits1..5); lane owns dims 8g..8g+7 and codes
// {4*c2+m}. Per token: in-lane f64 dots, fold masks {2,4} + mask {32}
// plain sum. Per 4-token batch: transpose-fold masks {8,16} (token
// tau = 2*b3+b4, dup over b5), packed-key argmin masks {1,2,4}.
//
// Round-12: round-11 structure, spill fixed. (128,5) clamped VGPR to 48
// -> wholesale spill (FETCH 131->686 MB, 312us). Occupancy must come
// from LDS sizing, NOT the register cap: (128,2) leaves cap=256 (natural
// ~68), LDS 16KB/block -> 10 blocks/CU -> 5 waves/SIMD (2x round 10).
// vmcnt ledger per {4L,5S} batch: S S | w4 CT S | w9 CT S ... | w9 CT | w5 CT.

#define NC    8
#define DIM   256
#define TPW   32           // tokens per wave
#define WPB   2            // waves per block
#define THREADS (WPB * 64)
#define BATCH 4

typedef float f32x4 __attribute__((ext_vector_type(4)));

#define WAITV(n) do { \
    asm volatile("s_waitcnt vmcnt(" #n ")" ::: "memory"); \
    __builtin_amdgcn_sched_barrier(0); \
} while (0)

__global__ __launch_bounds__(THREADS, 2)
void vq_kernel(const float* __restrict__ z, const float* __restrict__ emb,
               float* __restrict__ zq, float* __restrict__ fidx)
{
    // 2 waves x 2 buffers x 4 tokens x 1KB = 16 KB/block -> 10 blocks/CU
    __shared__ float lds[WPB][2][BATCH * DIM];

    const int lane = threadIdx.x & 63;
    const int w    = threadIdx.x >> 6;
    const int wid  = blockIdx.x * WPB + w;

    const int c2 = lane & 1;
    const int b1 = (lane >> 1) & 1, b2 = (lane >> 2) & 1;
    const int b3 = (lane >> 3) & 1, b4 = (lane >> 4) & 1, b5 = (lane >> 5) & 1;
    const int kappa = 4 * c2 + 2 * b1 + b2;   // code this lane owns post-fold
    const int gidx  = lane & 7;               // lane within 8-lane group
    const int tau   = 2 * b3 + b4;            // batch-local token post-transpose

    // emb fragments in f32 (64-reg footprint proven in round 7; cvt at
    // use is exact and rematerializable)
    float e32[4][8];
#pragma unroll
    for (int m = 0; m < 4; ++m) {
        const int row = 4 * c2 + m;
        const float4 ea = *reinterpret_cast<const float4*>(emb + row * DIM + 4 * lane);
        const float4 eb = *reinterpret_cast<const float4*>(emb + row * DIM + 4 * (lane ^ 1));
        e32[m][0] = ea.x; e32[m][1] = ea.y; e32[m][2] = ea.z; e32[m][3] = ea.w;
        e32[m][4] = eb.x; e32[m][5] = eb.y; e32[m][6] = eb.z; e32[m][7] = eb.w;
    }

    // ||e_kappa||^2 (one-time, f64-exact; plain 64-lane sum)
    double es[4];
#pragma unroll
    for (int m = 0; m < 4; ++m) {
        double s = 0.0;
#pragma unroll
        for (int j = 0; j < 8; ++j) {
            const double e = (double)e32[m][j];
            s += e * e;
        }
        es[m] = s;
    }
    double est[2];
#pragma unroll
    for (int i = 0; i < 2; ++i) {
        double keep = b1 ? es[i + 2] : es[i];
        double send = b1 ? es[i]     : es[i + 2];
        est[i] = keep + __shfl_xor(send, 2, 64);
    }
    double esv = (b2 ? est[1] : est[0]) + __shfl_xor(b2 ? est[0] : est[1], 4, 64);
    esv += __shfl_xor(esv, 8, 64);
    esv += __shfl_xor(esv, 16, 64);
    esv += __shfl_xor(esv, 32, 64);
    const double esq_my = esv;   // ||e_kappa||^2, exact f64

    const long long tok0 = (long long)wid * TPW;

    double val[BATCH];

    // ---- stage one 4-token batch into a per-wave LDS buffer ----
    // global_load_lds width=16: LDS dst is wave-uniform base + lane*16
    // -> linear row layout (exactly how we read it back).
    auto STAGE = [&](int bufi, int bidx) {
        const float* s = z + (tok0 + (long long)bidx * BATCH) * DIM + 4 * lane;
        float* d = &lds[w][bufi][0];
#pragma unroll
        for (int t = 0; t < BATCH; ++t)
            __builtin_amdgcn_global_load_lds(
                (const unsigned int*)(s + (size_t)t * DIM),
                (unsigned int*)(d + t * DIM), 16, 0, 0);
    };

    // ---- compute 4 tokens from an LDS buffer -> val[0..3] ----
    auto COMPUTE = [&](int bufi) {
        const float* bb = &lds[w][bufi][0];
#pragma unroll
        for (int t = 0; t < BATCH; ++t) {
            const float4 cA = *reinterpret_cast<const float4*>(bb + t * DIM + 4 * lane);
            const float4 cB = *reinterpret_cast<const float4*>(bb + t * DIM + 4 * (lane ^ 1));
            double acc[4];
            {
                const double z0 = cA.x, z1 = cA.y, z2 = cA.z, z3 = cA.w;
#pragma unroll
                for (int m = 0; m < 4; ++m)
                    acc[m] = (z0 * (double)e32[m][0] + z1 * (double)e32[m][1])
                           + (z2 * (double)e32[m][2] + z3 * (double)e32[m][3]);
            }
            {
                const double z4 = cB.x, z5 = cB.y, z6 = cB.z, z7 = cB.w;
#pragma unroll
                for (int m = 0; m < 4; ++m)
                    acc[m] += (z4 * (double)e32[m][4] + z5 * (double)e32[m][5])
                            + (z6 * (double)e32[m][6] + z7 * (double)e32[m][7]);
            }
            // fold masks {2,4} -> per-lane partial (code kappa, 32 dims)
            double ft[2];
#pragma unroll
            for (int i = 0; i < 2; ++i) {
                double keep = b1 ? acc[i + 2] : acc[i];
                double send = b1 ? acc[i]     : acc[i + 2];
                ft[i] = keep + __shfl_xor(send, 2, 64);
            }
            double v = (b2 ? ft[1] : ft[0]) + __shfl_xor(b2 ? ft[0] : ft[1], 4, 64);
            // mask {32} plain sum -> (code kappa, 64 dims), dup over b5
            val[t] = v + __shfl_xor(v, 32, 64);
        }
    };

    // ---- batched tail: 2-level transpose-fold, argmin, stores ----
    auto TAIL = [&](int bidx) {
        double tt[2];
#pragma unroll
        for (int i = 0; i < 2; ++i) {
            double keep = b3 ? val[i + 2] : val[i];
            double send = b3 ? val[i]     : val[i + 2];
            tt[i] = keep + __shfl_xor(send, 8, 64);
        }
        const double dot = (b4 ? tt[1] : tt[0]) + __shfl_xor(b4 ? tt[0] : tt[1], 16, 64);

        // argmin of ||z||^2 + ||e||^2 - 2 z.e == argmin of ||e||^2 - 2 z.e
        const double dist = esq_my - 2.0 * dot;

        // order-preserving f64 -> u64 key, code idx in low 3 bits
        unsigned long long u = (unsigned long long)__double_as_longlong(dist);
        u = (u >> 63) ? ~u : (u | 0x8000000000000000ULL);
        unsigned long long key = (u & ~7ULL) | (unsigned long long)kappa;
#pragma unroll
        for (int m = 1; m <= 4; m <<= 1) {
            unsigned long long ok = __shfl_xor(key, m, 64);
            key = (ok < key) ? ok : key;
        }
        const int widx = (int)(key & 7ULL);   // winner for token tau

        // cooperative z_q write: 16 lanes (b5 dup) own token tau; lane
        // writes chunks gidx+8*b5+16*j. Nontemporal full-line stores.
        const long long row = tok0 + (long long)bidx * BATCH + tau;
        float* qrow = zq + row * DIM;
        const float* erow = emb + widx * DIM;
#pragma unroll
        for (int j = 0; j < 4; ++j) {
            const int ch = gidx + 8 * b5 + 16 * j;
            const f32x4 q = *reinterpret_cast<const f32x4*>(erow + 4 * ch);
            __builtin_nontemporal_store(q, reinterpret_cast<f32x4*>(qrow + 4 * ch));
        }
        if (gidx == 0 && b5 == 0) fidx[row] = (float)widx;   // 4 lanes, 4 rows
    };

    // ---- pipelined schedule: counted vmcnt, never 0 mid-loop ----
    // per batch: 4 loads (STAGE), 5 stores (TAIL)
    STAGE(0, 0); STAGE(1, 1);

    WAITV(4); COMPUTE(0); TAIL(0); STAGE(0, 2);   // younger: b1's 4L
    WAITV(9); COMPUTE(1); TAIL(1); STAGE(1, 3);   // younger: 5S + 4L
    WAITV(9); COMPUTE(0); TAIL(2); STAGE(0, 4);
    WAITV(9); COMPUTE(1); TAIL(3); STAGE(1, 5);
    WAITV(9); COMPUTE(0); TAIL(4); STAGE(0, 6);
    WAITV(9); COMPUTE(1); TAIL(5); STAGE(1, 7);
    WAITV(9); COMPUTE(0); TAIL(6);                // younger: 5S + 4L
    WAITV(5); COMPUTE(1); TAIL(7);                // younger: tail6's 5S
}

extern "C" void kernel_launch(void* const* d_in, const int* in_sizes, int n_in,
                              void* d_out, int out_size, void* d_ws, size_t ws_size,
                              hipStream_t stream)
{
    const float* z   = (const float*)d_in[0];
    const float* emb = (const float*)d_in[1];
    float* out = (float*)d_out;

    const long long ntok = (long long)in_sizes[0] / DIM;   // 262144
    float* zq   = out;
    float* fidx = out + (size_t)ntok * DIM;

    const int blocks = (int)(ntok / (TPW * WPB));          // 4096

    vq_kernel<<<blocks, THREADS, 0, stream>>>(z, emb, zq, fidx);
}

// Round 13
// 95.818 us; speedup vs baseline: 3.2578x; 1.0280x over previous
//
#include <hip/hip_runtime.h>

// ActionVectorQuantizer: z [8*32768, 256] f32, emb [8, 256] f32
// out0 = emb[argmin_c ||z-e_c||^2] (f32), out1 = idx stored as f32.
//
// Math (verified 7x, f64-exact products, first-occurrence tie-break):
// lane = (c2=bit0, g=bits1..5); lane owns dims 8g..8g+7 and codes
// {4*c2+m}. Per token: in-lane f64 dots, fold masks {2,4} + mask {32}
// plain sum. Per 4-token batch: transpose-fold masks {8,16} (token
// tau = 2*b3+b4, dup over b5), packed-key argmin masks {1,2,4}.
//
// Round-13: two-phase split. vmcnt retires IN ORDER, so round-12's
// WAITV(9) stalled on the previous tail's 5 NT-store acks (~1000cy,
// HBM round-trip) every iteration -- which is also why 2x occupancy
// (round 12) didn't help. Phase 1: pure-load pipeline, WAITV(4) exact;
// result compressed to 3 bits/batch in a u32 (wkeys). Phase 2 (after a
// sched_barrier fence): all z_q/idx stores streamed, no waits -- the
// kernel-end drain pays store latency exactly once.

#define NC    8
#define DIM   256
#define TPW   32           // tokens per wave
#define WPB   2            // waves per block
#define THREADS (WPB * 64)
#define BATCH 4

typedef float f32x4 __attribute__((ext_vector_type(4)));

#define WAITV(n) do { \
    asm volatile("s_waitcnt vmcnt(" #n ")" ::: "memory"); \
    __builtin_amdgcn_sched_barrier(0); \
} while (0)

__global__ __launch_bounds__(THREADS, 2)
void vq_kernel(const float* __restrict__ z, const float* __restrict__ emb,
               float* __restrict__ zq, float* __restrict__ fidx)
{
    // 2 waves x 2 buffers x 4 tokens x 1KB = 16 KB/block -> 10 blocks/CU
    __shared__ float lds[WPB][2][BATCH * DIM];

    const int lane = threadIdx.x & 63;
    const int w    = threadIdx.x >> 6;
    const int wid  = blockIdx.x * WPB + w;

    const int c2 = lane & 1;
    const int b1 = (lane >> 1) & 1, b2 = (lane >> 2) & 1;
    const int b3 = (lane >> 3) & 1, b4 = (lane >> 4) & 1, b5 = (lane >> 5) & 1;
    const int kappa = 4 * c2 + 2 * b1 + b2;   // code this lane owns post-fold
    const int gidx  = lane & 7;               // lane within 8-lane group
    const int tau   = 2 * b3 + b4;            // batch-local token post-transpose

    // emb fragments in f32 (remat-exact cvt at use; 64-reg proven)
    float e32[4][8];
#pragma unroll
    for (int m = 0; m < 4; ++m) {
        const int row = 4 * c2 + m;
        const float4 ea = *reinterpret_cast<const float4*>(emb + row * DIM + 4 * lane);
        const float4 eb = *reinterpret_cast<const float4*>(emb + row * DIM + 4 * (lane ^ 1));
        e32[m][0] = ea.x; e32[m][1] = ea.y; e32[m][2] = ea.z; e32[m][3] = ea.w;
        e32[m][4] = eb.x; e32[m][5] = eb.y; e32[m][6] = eb.z; e32[m][7] = eb.w;
    }

    // ||e_kappa||^2 (one-time, f64-exact)
    double es[4];
#pragma unroll
    for (int m = 0; m < 4; ++m) {
        double s = 0.0;
#pragma unroll
        for (int j = 0; j < 8; ++j) {
            const double e = (double)e32[m][j];
            s += e * e;
        }
        es[m] = s;
    }
    double est[2];
#pragma unroll
    for (int i = 0; i < 2; ++i) {
        double keep = b1 ? es[i + 2] : es[i];
        double send = b1 ? es[i]     : es[i + 2];
        est[i] = keep + __shfl_xor(send, 2, 64);
    }
    double esv = (b2 ? est[1] : est[0]) + __shfl_xor(b2 ? est[0] : est[1], 4, 64);
    esv += __shfl_xor(esv, 8, 64);
    esv += __shfl_xor(esv, 16, 64);
    esv += __shfl_xor(esv, 32, 64);
    const double esq_my = esv;   // ||e_kappa||^2, exact f64

    const long long tok0 = (long long)wid * TPW;

    double val[BATCH];

    // ---- stage one 4-token batch into a per-wave LDS buffer ----
    // global_load_lds width=16: LDS dst is wave-uniform base + lane*16
    // -> linear row layout (exactly how we read it back).
    auto STAGE = [&](int bufi, int bidx) {
        const float* s = z + (tok0 + (long long)bidx * BATCH) * DIM + 4 * lane;
        float* d = &lds[w][bufi][0];
#pragma unroll
        for (int t = 0; t < BATCH; ++t)
            __builtin_amdgcn_global_load_lds(
                (const unsigned int*)(s + (size_t)t * DIM),
                (unsigned int*)(d + t * DIM), 16, 0, 0);
    };

    // ---- compute 4 tokens from an LDS buffer -> val[0..3] ----
    auto COMPUTE = [&](int bufi) {
        const float* bb = &lds[w][bufi][0];
#pragma unroll
        for (int t = 0; t < BATCH; ++t) {
            const float4 cA = *reinterpret_cast<const float4*>(bb + t * DIM + 4 * lane);
            const float4 cB = *reinterpret_cast<const float4*>(bb + t * DIM + 4 * (lane ^ 1));
            double acc[4];
            {
                const double z0 = cA.x, z1 = cA.y, z2 = cA.z, z3 = cA.w;
#pragma unroll
                for (int m = 0; m < 4; ++m)
                    acc[m] = (z0 * (double)e32[m][0] + z1 * (double)e32[m][1])
                           + (z2 * (double)e32[m][2] + z3 * (double)e32[m][3]);
            }
            {
                const double z4 = cB.x, z5 = cB.y, z6 = cB.z, z7 = cB.w;
#pragma unroll
                for (int m = 0; m < 4; ++m)
                    acc[m] += (z4 * (double)e32[m][4] + z5 * (double)e32[m][5])
                            + (z6 * (double)e32[m][6] + z7 * (double)e32[m][7]);
            }
            // fold masks {2,4} -> per-lane partial (code kappa, 32 dims)
            double ft[2];
#pragma unroll
            for (int i = 0; i < 2; ++i) {
                double keep = b1 ? acc[i + 2] : acc[i];
                double send = b1 ? acc[i]     : acc[i + 2];
                ft[i] = keep + __shfl_xor(send, 2, 64);
            }
            double v = (b2 ? ft[1] : ft[0]) + __shfl_xor(b2 ? ft[0] : ft[1], 4, 64);
            // mask {32} plain sum -> (code kappa, 64 dims), dup over b5
            val[t] = v + __shfl_xor(v, 32, 64);
        }
    };

    // ---- fold + argmin for one batch -> 3-bit winner for token tau ----
    auto ARGMIN = [&]() -> unsigned int {
        double tt[2];
#pragma unroll
        for (int i = 0; i < 2; ++i) {
            double keep = b3 ? val[i + 2] : val[i];
            double send = b3 ? val[i]     : val[i + 2];
            tt[i] = keep + __shfl_xor(send, 8, 64);
        }
        const double dot = (b4 ? tt[1] : tt[0]) + __shfl_xor(b4 ? tt[0] : tt[1], 16, 64);

        // argmin of ||z||^2 + ||e||^2 - 2 z.e == argmin of ||e||^2 - 2 z.e
        const double dist = esq_my - 2.0 * dot;

        // order-preserving f64 -> u64 key, code idx in low 3 bits
        unsigned long long u = (unsigned long long)__double_as_longlong(dist);
        u = (u >> 63) ? ~u : (u | 0x8000000000000000ULL);
        unsigned long long key = (u & ~7ULL) | (unsigned long long)kappa;
#pragma unroll
        for (int m = 1; m <= 4; m <<= 1) {
            unsigned long long ok = __shfl_xor(key, m, 64);
            key = (ok < key) ? ok : key;
        }
        return (unsigned int)(key & 7ULL);   // winner for token tau
    };

    // ================= phase 1: pure-load pipeline =================
    // per batch: 4 loads; waits are exactly vmcnt(4) (no stores in the
    // counter). wkeys packs widx (3 bits) per batch.
    unsigned int wkeys = 0;

    STAGE(0, 0); STAGE(1, 1);

    WAITV(4); COMPUTE(0); wkeys |= ARGMIN() <<  0; STAGE(0, 2);
    WAITV(4); COMPUTE(1); wkeys |= ARGMIN() <<  3; STAGE(1, 3);
    WAITV(4); COMPUTE(0); wkeys |= ARGMIN() <<  6; STAGE(0, 4);
    WAITV(4); COMPUTE(1); wkeys |= ARGMIN() <<  9; STAGE(1, 5);
    WAITV(4); COMPUTE(0); wkeys |= ARGMIN() << 12; STAGE(0, 6);
    WAITV(4); COMPUTE(1); wkeys |= ARGMIN() << 15; STAGE(1, 7);
    WAITV(4); COMPUTE(0); wkeys |= ARGMIN() << 18;
    WAITV(0); COMPUTE(1); wkeys |= ARGMIN() << 21;

    // fence: keep ALL stores after ALL phase-1 loads/waits
    __builtin_amdgcn_sched_barrier(0);

    // ================= phase 2: store streaming (no waits) =========
    // 16 lanes (b5 dup) own token tau of each batch; lane writes chunks
    // gidx+8*b5+16*j. NT full-line stores (never re-read, keep L3 for z).
    // Store latency is paid once, at the kernel-end implicit drain.
#pragma unroll
    for (int b = 0; b < 8; ++b) {
        const int widx = (int)((wkeys >> (3 * b)) & 7u);
        const long long row = tok0 + (long long)b * BATCH + tau;
        float* qrow = zq + row * DIM;
        const float* erow = emb + widx * DIM;   // L1-hot (8 KB table)
#pragma unroll
        for (int j = 0; j < 4; ++j) {
            const int ch = gidx + 8 * b5 + 16 * j;
            const f32x4 q = *reinterpret_cast<const f32x4*>(erow + 4 * ch);
            __builtin_nontemporal_store(q, reinterpret_cast<f32x4*>(qrow + 4 * ch));
        }
        if (gidx == 0 && b5 == 0) fidx[row] = (float)widx;   // 4 lanes, 4 rows
    }
}

extern "C" void kernel_launch(void* const* d_in, const int* in_sizes, int n_in,
                              void* d_out, int out_size, void* d_ws, size_t ws_size,
                              hipStream_t stream)
{
    const float* z   = (const float*)d_in[0];
    const float* emb = (const float*)d_in[1];
    float* out = (float*)d_out;

    const long long ntok = (long long)in_sizes[0] / DIM;   // 262144
    float* zq   = out;
    float* fidx = out + (size_t)ntok * DIM;

    const int blocks = (int)(ntok / (TPW * WPB));          // 4096

    vq_kernel<<<blocks, THREADS, 0, stream>>>(z, emb, zq, fidx);
}

// Round 14
// 95.441 us; speedup vs baseline: 3.2707x; 1.0040x over previous
//
#include <hip/hip_runtime.h>

// ActionVectorQuantizer: z [8*32768, 256] f32, emb [8, 256] f32
// out0 = emb[argmin_c ||z-e_c||^2] (f32), out1 = idx stored as f32.
//
// Math (verified 8x, f64-exact products, first-occurrence tie-break):
// lane = (c2=bit0, g=bits1..5); lane owns dims 8g..8g+7 and codes
// {4*c2+m}. Per token: in-lane f64 dots, fold masks {2,4} + mask {32}
// plain sum. Per 4-token batch: transpose-fold masks {8,16} (token
// tau = 2*b3+b4, dup over b5), packed-key argmin masks {1,2,4}.
//
// Round-14: cut per-token VALU. Rounds 10/12/13 plateau 95-98us with
// VALUBusy ~38% (real-time scaled): the f32 e-table costs 32 remat cvts
// per token on top of 32 f64 FMA. Keep e-table in f64 REGISTERS (z cvt'd
// once: 8 cvt/token) -> ~170 vs ~256 SIMD-cyc/token. VGPR ~115 stays in
// the same <=128 bucket (4 waves/SIMD) and far under (128,2)'s 256 cap
// -> no spill (round-9-proven e64 residency). Memory schedule identical
// to round 13: pure-load vmcnt ledger, phase-2 deferred NT stores.

#define NC    8
#define DIM   256
#define TPW   32           // tokens per wave
#define WPB   2            // waves per block
#define THREADS (WPB * 64)
#define BATCH 4

typedef float f32x4 __attribute__((ext_vector_type(4)));

#define WAITV(n) do { \
    asm volatile("s_waitcnt vmcnt(" #n ")" ::: "memory"); \
    __builtin_amdgcn_sched_barrier(0); \
} while (0)

__global__ __launch_bounds__(THREADS, 2)
void vq_kernel(const float* __restrict__ z, const float* __restrict__ emb,
               float* __restrict__ zq, float* __restrict__ fidx)
{
    // 2 waves x 2 buffers x 4 tokens x 1KB = 16 KB/block -> 10 blocks/CU
    __shared__ float lds[WPB][2][BATCH * DIM];

    const int lane = threadIdx.x & 63;
    const int w    = threadIdx.x >> 6;
    const int wid  = blockIdx.x * WPB + w;

    const int c2 = lane & 1;
    const int b1 = (lane >> 1) & 1, b2 = (lane >> 2) & 1;
    const int b3 = (lane >> 3) & 1, b4 = (lane >> 4) & 1, b5 = (lane >> 5) & 1;
    const int kappa = 4 * c2 + 2 * b1 + b2;   // code this lane owns post-fold
    const int gidx  = lane & 7;               // lane within 8-lane group
    const int tau   = 2 * b3 + b4;            // batch-local token post-transpose

    // emb fragments resident in f64 (64 VGPR): no per-token e-cvt.
    // [m][0..3] <-> chunk `lane`, [4..7] <-> chunk `lane^1`.
    double e64[4][8];
#pragma unroll
    for (int m = 0; m < 4; ++m) {
        const int row = 4 * c2 + m;
        const float4 ea = *reinterpret_cast<const float4*>(emb + row * DIM + 4 * lane);
        const float4 eb = *reinterpret_cast<const float4*>(emb + row * DIM + 4 * (lane ^ 1));
        e64[m][0] = ea.x; e64[m][1] = ea.y; e64[m][2] = ea.z; e64[m][3] = ea.w;
        e64[m][4] = eb.x; e64[m][5] = eb.y; e64[m][6] = eb.z; e64[m][7] = eb.w;
    }

    // ||e_kappa||^2 (one-time, f64-exact)
    double es[4];
#pragma unroll
    for (int m = 0; m < 4; ++m) {
        double s = 0.0;
#pragma unroll
        for (int j = 0; j < 8; ++j) s += e64[m][j] * e64[m][j];
        es[m] = s;
    }
    double est[2];
#pragma unroll
    for (int i = 0; i < 2; ++i) {
        double keep = b1 ? es[i + 2] : es[i];
        double send = b1 ? es[i]     : es[i + 2];
        est[i] = keep + __shfl_xor(send, 2, 64);
    }
    double esv = (b2 ? est[1] : est[0]) + __shfl_xor(b2 ? est[0] : est[1], 4, 64);
    esv += __shfl_xor(esv, 8, 64);
    esv += __shfl_xor(esv, 16, 64);
    esv += __shfl_xor(esv, 32, 64);
    const double esq_my = esv;   // ||e_kappa||^2, exact f64

    const long long tok0 = (long long)wid * TPW;

    double val[BATCH];

    // ---- stage one 4-token batch into a per-wave LDS buffer ----
    // global_load_lds width=16: LDS dst is wave-uniform base + lane*16
    // -> linear row layout (exactly how we read it back).
    auto STAGE = [&](int bufi, int bidx) {
        const float* s = z + (tok0 + (long long)bidx * BATCH) * DIM + 4 * lane;
        float* d = &lds[w][bufi][0];
#pragma unroll
        for (int t = 0; t < BATCH; ++t)
            __builtin_amdgcn_global_load_lds(
                (const unsigned int*)(s + (size_t)t * DIM),
                (unsigned int*)(d + t * DIM), 16, 0, 0);
    };

    // ---- compute 4 tokens from an LDS buffer -> val[0..3] ----
    auto COMPUTE = [&](int bufi) {
        const float* bb = &lds[w][bufi][0];
#pragma unroll
        for (int t = 0; t < BATCH; ++t) {
            const float4 cA = *reinterpret_cast<const float4*>(bb + t * DIM + 4 * lane);
            const float4 cB = *reinterpret_cast<const float4*>(bb + t * DIM + 4 * (lane ^ 1));
            // z converted ONCE per token (8 cvt), e already f64
            double acc[4];
            {
                const double z0 = cA.x, z1 = cA.y, z2 = cA.z, z3 = cA.w;
#pragma unroll
                for (int m = 0; m < 4; ++m)
                    acc[m] = (z0 * e64[m][0] + z1 * e64[m][1])
                           + (z2 * e64[m][2] + z3 * e64[m][3]);
            }
            {
                const double z4 = cB.x, z5 = cB.y, z6 = cB.z, z7 = cB.w;
#pragma unroll
                for (int m = 0; m < 4; ++m)
                    acc[m] += (z4 * e64[m][4] + z5 * e64[m][5])
                            + (z6 * e64[m][6] + z7 * e64[m][7]);
            }
            // fold masks {2,4} -> per-lane partial (code kappa, 32 dims)
            double ft[2];
#pragma unroll
            for (int i = 0; i < 2; ++i) {
                double keep = b1 ? acc[i + 2] : acc[i];
                double send = b1 ? acc[i]     : acc[i + 2];
                ft[i] = keep + __shfl_xor(send, 2, 64);
            }
            double v = (b2 ? ft[1] : ft[0]) + __shfl_xor(b2 ? ft[0] : ft[1], 4, 64);
            // mask {32} plain sum -> (code kappa, 64 dims), dup over b5
            val[t] = v + __shfl_xor(v, 32, 64);
        }
    };

    // ---- fold + argmin for one batch -> 3-bit winner for token tau ----
    auto ARGMIN = [&]() -> unsigned int {
        double tt[2];
#pragma unroll
        for (int i = 0; i < 2; ++i) {
            double keep = b3 ? val[i + 2] : val[i];
            double send = b3 ? val[i]     : val[i + 2];
            tt[i] = keep + __shfl_xor(send, 8, 64);
        }
        const double dot = (b4 ? tt[1] : tt[0]) + __shfl_xor(b4 ? tt[0] : tt[1], 16, 64);

        // argmin of ||z||^2 + ||e||^2 - 2 z.e == argmin of ||e||^2 - 2 z.e
        const double dist = esq_my - 2.0 * dot;

        // order-preserving f64 -> u64 key, code idx in low 3 bits
        unsigned long long u = (unsigned long long)__double_as_longlong(dist);
        u = (u >> 63) ? ~u : (u | 0x8000000000000000ULL);
        unsigned long long key = (u & ~7ULL) | (unsigned long long)kappa;
#pragma unroll
        for (int m = 1; m <= 4; m <<= 1) {
            unsigned long long ok = __shfl_xor(key, m, 64);
            key = (ok < key) ? ok : key;
        }
        return (unsigned int)(key & 7ULL);   // winner for token tau
    };

    // ================= phase 1: pure-load pipeline =================
    // per batch: 4 loads; waits are exactly vmcnt(4) (no stores in the
    // counter). wkeys packs widx (3 bits) per batch.
    unsigned int wkeys = 0;

    STAGE(0, 0); STAGE(1, 1);

    WAITV(4); COMPUTE(0); wkeys |= ARGMIN() <<  0; STAGE(0, 2);
    WAITV(4); COMPUTE(1); wkeys |= ARGMIN() <<  3; STAGE(1, 3);
    WAITV(4); COMPUTE(0); wkeys |= ARGMIN() <<  6; STAGE(0, 4);
    WAITV(4); COMPUTE(1); wkeys |= ARGMIN() <<  9; STAGE(1, 5);
    WAITV(4); COMPUTE(0); wkeys |= ARGMIN() << 12; STAGE(0, 6);
    WAITV(4); COMPUTE(1); wkeys |= ARGMIN() << 15; STAGE(1, 7);
    WAITV(4); COMPUTE(0); wkeys |= ARGMIN() << 18;
    WAITV(0); COMPUTE(1); wkeys |= ARGMIN() << 21;

    // fence: keep ALL stores after ALL phase-1 loads/waits
    __builtin_amdgcn_sched_barrier(0);

    // ================= phase 2: store streaming (no waits) =========
    // 16 lanes (b5 dup) own token tau of each batch; lane writes chunks
    // gidx+8*b5+16*j. NT full-line stores (never re-read, keep L3 for z).
    // Store latency is paid once, at the kernel-end implicit drain.
#pragma unroll
    for (int b = 0; b < 8; ++b) {
        const int widx = (int)((wkeys >> (3 * b)) & 7u);
        const long long row = tok0 + (long long)b * BATCH + tau;
        float* qrow = zq + row * DIM;
        const float* erow = emb + widx * DIM;   // L1-hot (8 KB table)
#pragma unroll
        for (int j = 0; j < 4; ++j) {
            const int ch = gidx + 8 * b5 + 16 * j;
            const f32x4 q = *reinterpret_cast<const f32x4*>(erow + 4 * ch);
            __builtin_nontemporal_store(q, reinterpret_cast<f32x4*>(qrow + 4 * ch));
        }
        if (gidx == 0 && b5 == 0) fidx[row] = (float)widx;   // 4 lanes, 4 rows
    }
}

extern "C" void kernel_launch(void* const* d_in, const int* in_sizes, int n_in,
                              void* d_out, int out_size, void* d_ws, size_t ws_size,
                              hipStream_t stream)
{
    const float* z   = (const float*)d_in[0];
    const float* emb = (const float*)d_in[1];
    float* out = (float*)d_out;

    const long long ntok = (long long)in_sizes[0] / DIM;   // 262144
    float* zq   = out;
    float* fidx = out + (size_t)ntok * DIM;

    const int blocks = (int)(ntok / (TPW * WPB));          // 4096

    vq_kernel<<<blocks, THREADS, 0, stream>>>(z, emb, zq, fidx);
}